// Round 3
// baseline (732.247 us; speedup 1.0000x reference)
//
#include <hip/hip_runtime.h>
#include <cfloat>
#include <cmath>
#include <stdint.h>

#define N 8192
#define D 512
#define K 16
#define RB 128     // rows per k_knn block
#define SLICES 8
#define JS 1024    // cols per slice
#define JT 128     // j-tile width
#define KC 64      // k chunk (bf16 elems) = 8 chunks of 16B
#define NCH (D / KC)
#define CAP 16     // survivor slots per row per pass
#define NPART (SLICES * K)   // 128 partial entries per row

typedef __bf16 bf16x8 __attribute__((ext_vector_type(8)));
typedef __bf16 bf16x4 __attribute__((ext_vector_type(4)));
typedef float  f32x16 __attribute__((ext_vector_type(16)));
typedef float  f32x4  __attribute__((ext_vector_type(4)));

// ---------------- kernel 1: cast to bf16 + row squared norms (fp32) ----------
__global__ __launch_bounds__(256)
void k_cast_sqnorm(const float* __restrict__ emb, float* __restrict__ sq,
                   __bf16* __restrict__ embh) {
    int row = blockIdx.x * 4 + (threadIdx.x >> 6);
    int lane = threadIdx.x & 63;
    const float4* e = (const float4*)(emb + (size_t)row * D);
    float s = 0.f;
    #pragma unroll
    for (int c = 0; c < 2; c++) {
        float4 v = e[lane + 64 * c];
        s += v.x * v.x + v.y * v.y + v.z * v.z + v.w * v.w;
        bf16x4 h = { (__bf16)v.x, (__bf16)v.y, (__bf16)v.z, (__bf16)v.w };
        *(bf16x4*)&embh[(size_t)row * D + (size_t)(lane + 64 * c) * 4] = h;
    }
    for (int off = 32; off; off >>= 1) s += __shfl_down(s, off, 64);
    if (lane == 0) sq[row] = s;
}

// ---------------- kernel 2: MFMA distance GEMM + streaming top-16 ------------
// grid 512: rg = bid>>3 (128 rows), sl = bid&7 (1024-col slice).
// 4 waves, wave tile 64x64 = 4 x mfma_32x32x16_bf16 accumulators.
// LDS A/B tiles XOR-swizzled (16B chunk c ^= row&7): conflict-free b128 frag
// reads AND staging writes. Selection arrays transposed [K][RB]: bank-per-lane.
__global__ __launch_bounds__(256, 2)
void k_knn(const __bf16* __restrict__ embh, const float* __restrict__ sq,
           float* __restrict__ pd2, int* __restrict__ pidx) {
    __shared__ uint4 As4[RB * 8];          // 16 KB
    __shared__ uint4 Bs4[JT * 8];          // 16 KB
    __shared__ float svD[CAP][RB];         // 8 KB
    __shared__ int   svI[CAP][RB];         // 8 KB
    __shared__ float listD[K][RB];         // 8 KB
    __shared__ int   listI[K][RB];         // 8 KB
    __shared__ float sqr[RB], kadj[RB], kmaxA[RB];
    __shared__ int   scount[RB];
    __shared__ int   again;

    const int t   = threadIdx.x;
    const int rg  = blockIdx.x >> 3;
    const int sl  = blockIdx.x & 7;
    const int ib  = rg * RB;
    const int jsb = sl * JS;
    const int lane = t & 63, quad = lane >> 5, l31 = lane & 31;
    const int w  = t >> 6;
    const int wr = (w >> 1) * 64;
    const int wc = (w & 1) * 64;
    const int sr = t >> 3;     // staging: base row (8 rows per 64-lane group)
    const int sg = t & 7;      // staging: 16B granule within row chunk

    if (t < RB) {
        sqr[t] = sq[ib + t];
        kadj[t] = FLT_MAX; kmaxA[t] = FLT_MAX; scount[t] = 0;
    }
    if (t < RB) {
        #pragma unroll
        for (int q = 0; q < K; q++) { listD[q][t] = FLT_MAX; listI[q][t] = 0; }
    }
    if (t == 0) again = 0;
    __syncthreads();

    for (int jt = 0; jt < JS / JT; jt++) {
        const int jb = jsb + jt * JT;
        f32x16 z = {};
        f32x16 acc[2][2];
        acc[0][0] = z; acc[0][1] = z; acc[1][0] = z; acc[1][1] = z;

        // stage chunk 0 (swizzled)
        #pragma unroll
        for (int q = 0; q < 4; q++) {
            int row = sr + 32 * q;
            As4[row * 8 + (sg ^ (row & 7))] = *(const uint4*)&embh[(size_t)(ib + row) * D + sg * 8];
            Bs4[row * 8 + (sg ^ (row & 7))] = *(const uint4*)&embh[(size_t)(jb + row) * D + sg * 8];
        }
        __syncthreads();

        uint4 pfA[4], pfB[4];
        for (int kc = 0; kc < NCH; kc++) {
            if (kc + 1 < NCH) {            // register prefetch of next chunk
                int k0 = (kc + 1) * KC;
                #pragma unroll
                for (int q = 0; q < 4; q++) {
                    int row = sr + 32 * q;
                    pfA[q] = *(const uint4*)&embh[(size_t)(ib + row) * D + k0 + sg * 8];
                    pfB[q] = *(const uint4*)&embh[(size_t)(jb + row) * D + k0 + sg * 8];
                }
            }
            #pragma unroll
            for (int kk = 0; kk < KC / 16; kk++) {
                int c = 2 * kk + quad;
                int ra0 = wr + l31, ra1 = wr + 32 + l31;
                int rb0 = wc + l31, rb1 = wc + 32 + l31;
                bf16x8 a0 = __builtin_bit_cast(bf16x8, As4[ra0 * 8 + (c ^ (ra0 & 7))]);
                bf16x8 a1 = __builtin_bit_cast(bf16x8, As4[ra1 * 8 + (c ^ (ra1 & 7))]);
                bf16x8 b0 = __builtin_bit_cast(bf16x8, Bs4[rb0 * 8 + (c ^ (rb0 & 7))]);
                bf16x8 b1 = __builtin_bit_cast(bf16x8, Bs4[rb1 * 8 + (c ^ (rb1 & 7))]);
                acc[0][0] = __builtin_amdgcn_mfma_f32_32x32x16_bf16(a0, b0, acc[0][0], 0, 0, 0);
                acc[0][1] = __builtin_amdgcn_mfma_f32_32x32x16_bf16(a0, b1, acc[0][1], 0, 0, 0);
                acc[1][0] = __builtin_amdgcn_mfma_f32_32x32x16_bf16(a1, b0, acc[1][0], 0, 0, 0);
                acc[1][1] = __builtin_amdgcn_mfma_f32_32x32x16_bf16(a1, b1, acc[1][1], 0, 0, 0);
            }
            __syncthreads();               // all waves done reading As/Bs
            if (kc + 1 < NCH) {
                #pragma unroll
                for (int q = 0; q < 4; q++) {
                    int row = sr + 32 * q;
                    As4[row * 8 + (sg ^ (row & 7))] = pfA[q];
                    Bs4[row * 8 + (sg ^ (row & 7))] = pfB[q];
                }
                __syncthreads();           // next chunk visible
            }
        }

        // ---- selection: capped survivor buffer + dedupe mask + retry ----
        float sqc0 = sq[jb + wc + l31];
        float sqc1 = sq[jb + wc + 32 + l31];
        uint64_t mask = 0;
        while (true) {
            #pragma unroll
            for (int r = 0; r < 2; r++)
            #pragma unroll
            for (int c = 0; c < 2; c++)
            #pragma unroll
            for (int reg = 0; reg < 16; reg++) {
                int bit = ((r * 2 + c) << 4) | reg;
                if ((mask >> bit) & 1) continue;
                int row_l = wr + r * 32 + ((reg & 3) + ((reg >> 2) << 3) + (quad << 2));
                float t2 = (c ? sqc1 : sqc0) - 2.f * acc[r][c][reg];
                if (t2 < kadj[row_l]) {
                    int j = jb + wc + c * 32 + l31;
                    if (j != ib + row_l) {
                        int p = atomicAdd(&scount[row_l], 1);
                        if (p < CAP) {
                            svD[p][row_l] = t2 + sqr[row_l];
                            svI[p][row_l] = j;
                            mask |= (1ull << bit);
                        }
                    }
                }
            }
            __syncthreads();
            if (t < RB) {
                int cnt = scount[t];
                if (cnt) {
                    int m = cnt < CAP ? cnt : CAP;
                    float kmx = kmaxA[t];
                    for (int p = 0; p < m; p++) {
                        float d2 = svD[p][t];
                        if (d2 < kmx) {
                            int am = 0; float mx = listD[0][t];
                            #pragma unroll
                            for (int q = 1; q < K; q++)
                                if (listD[q][t] > mx) { mx = listD[q][t]; am = q; }
                            listD[am][t] = d2; listI[am][t] = svI[p][t];
                            mx = listD[0][t];
                            #pragma unroll
                            for (int q = 1; q < K; q++) mx = fmaxf(mx, listD[q][t]);
                            kmx = mx;
                        }
                    }
                    kmaxA[t] = kmx; kadj[t] = kmx - sqr[t];
                    scount[t] = 0;
                    if (cnt > CAP) again = 1;
                }
            }
            __syncthreads();
            int more = again;
            __syncthreads();               // protect 'again' before next clear
            if (more && t == 0) again = 0;
            if (!more) break;
        }
    }

    if (t < RB) {
        #pragma unroll
        for (int q = 0; q < K; q++) {
            pd2[(size_t)(ib + t) * NPART + sl * K + q]  = listD[q][t];
            pidx[(size_t)(ib + t) * NPART + sl * K + q] = listI[q][t];
        }
    }
}

// ---------------- kernel 3: merge 8 partial lists per row --------------------
__global__ __launch_bounds__(256)
void k_merge(const float* __restrict__ pd2, const int* __restrict__ pidx,
             int* __restrict__ knn, float* __restrict__ row_sum) {
    int row = blockIdx.x * 256 + threadIdx.x;
    float bd[K]; int bi[K];
    #pragma unroll
    for (int q = 0; q < K; q++) { bd[q] = FLT_MAX; bi[q] = 0; }
    float kmx = FLT_MAX;
    const float* pr = pd2 + (size_t)row * NPART;
    const int*   pi = pidx + (size_t)row * NPART;
    for (int s = 0; s < NPART; s++) {
        float d2 = pr[s];
        if (d2 < kmx) {
            int am = 0; float mx = bd[0];
            #pragma unroll
            for (int q = 1; q < K; q++) if (bd[q] > mx) { mx = bd[q]; am = q; }
            bd[am] = d2; bi[am] = pi[s];
            mx = bd[0];
            #pragma unroll
            for (int q = 1; q < K; q++) mx = fmaxf(mx, bd[q]);
            kmx = mx;
        }
    }
    float s = 0.f;
    #pragma unroll
    for (int q = 0; q < K; q++) {
        float d2 = bd[q];
        s += (d2 > 0.f) ? sqrtf(fmaxf(d2, 1e-12f)) : 0.f;
        knn[(size_t)row * K + q] = bi[q];
    }
    row_sum[row] = s;
}

// ---------------- kernel 4: per-row curvature via MFMA Gram ------------------
// 1 wave per row (4 rows/block). Gather 16 neighbors, cast bf16 to swizzled
// LDS, Gram = Nb*Nb^T via mfma_16x16x32 (A-frag == B-frag; k-permutation
// invariant so only the verified C-layout matters), all-pairs sqrt in-wave.
__global__ __launch_bounds__(256, 2)
void k_curv(const float* __restrict__ emb, const int* __restrict__ knn_idx,
            const float* __restrict__ row_sum, const float* __restrict__ ref_curv,
            float* __restrict__ curv_err) {
    __shared__ uint4 nb4[4][K * 64];       // 4 x 16 KB, swizzled
    __shared__ float Gm[4][K][K + 1];
    const int t = threadIdx.x;
    const int w = t >> 6, lane = t & 63;
    const int i = blockIdx.x * 4 + w;
    const int r = lane >> 2, qt = lane & 3;

    const int nrow = knn_idx[(size_t)i * K + r];
    const float* src = emb + (size_t)nrow * D + qt * 128;
    #pragma unroll
    for (int it = 0; it < 16; it++) {
        float4 f0 = *(const float4*)(src + it * 8);
        float4 f1 = *(const float4*)(src + it * 8 + 4);
        bf16x8 h = { (__bf16)f0.x, (__bf16)f0.y, (__bf16)f0.z, (__bf16)f0.w,
                     (__bf16)f1.x, (__bf16)f1.y, (__bf16)f1.z, (__bf16)f1.w };
        int c = qt * 16 + it;
        nb4[w][r * 64 + (c ^ (r & 7))] = __builtin_bit_cast(uint4, h);
    }
    __syncthreads();

    f32x4 acc = {};
    const int m = lane & 15, q4 = lane >> 4;
    #pragma unroll
    for (int ck = 0; ck < 16; ck++) {
        int c = ck * 4 + q4;
        bf16x8 fr = __builtin_bit_cast(bf16x8, nb4[w][m * 64 + (c ^ (m & 7))]);
        acc = __builtin_amdgcn_mfma_f32_16x16x32_bf16(fr, fr, acc, 0, 0, 0);
    }
    #pragma unroll
    for (int reg = 0; reg < 4; reg++)
        Gm[w][q4 * 4 + reg][m] = acc[reg];
    __syncthreads();

    float s = 0.f;
    #pragma unroll
    for (int q = 0; q < 4; q++) {
        int cell = lane + 64 * q;
        int j = cell >> 4, l = cell & 15;
        float d2 = Gm[w][j][j] + Gm[w][l][l] - 2.f * Gm[w][j][l];
        s += (d2 > 0.f) ? sqrtf(fmaxf(d2, 1e-12f)) : 0.f;   // diag contributes 0
    }
    for (int off = 32; off; off >>= 1) s += __shfl_down(s, off, 64);
    if (lane == 0) {
        float inter_mean = s * 0.5f / 120.f;
        float avg = row_sum[i] / 16.f;
        float curv = inter_mean / (avg + 1e-8f);
        float diff = curv - ref_curv[i];
        curv_err[i] = diff * diff;
    }
}

// ---------------- kernel 5: final scalar reduce ------------------------------
__global__ __launch_bounds__(1024)
void k_final(const float* __restrict__ curv_err, const float* __restrict__ row_sum,
             const float* __restrict__ ref_dist, float* __restrict__ out) {
    const int t = threadIdx.x;
    float s1 = 0.f, s2 = 0.f, s3 = 0.f;
    for (int i = t; i < N; i += 1024) { s1 += curv_err[i]; s2 += row_sum[i]; }
    for (int i = t; i < N * K; i += 1024) s3 += ref_dist[i];
    for (int off = 32; off; off >>= 1) {
        s1 += __shfl_down(s1, off, 64);
        s2 += __shfl_down(s2, off, 64);
        s3 += __shfl_down(s3, off, 64);
    }
    __shared__ float a1[16], a2[16], a3[16];
    int w = t >> 6, lane = t & 63;
    if (lane == 0) { a1[w] = s1; a2[w] = s2; a3[w] = s3; }
    __syncthreads();
    if (t == 0) {
        float t1 = 0.f, t2 = 0.f, t3 = 0.f;
        for (int q = 0; q < 16; q++) { t1 += a1[q]; t2 += a2[q]; t3 += a3[q]; }
        float curv_loss = t1 / (float)N;
        float dm = t2 / (float)(N * K);
        float rm = t3 / (float)(N * K);
        float d = dm - rm;
        out[0] = curv_loss + 0.1f * d * d;
    }
}

extern "C" void kernel_launch(void* const* d_in, const int* in_sizes, int n_in,
                              void* d_out, int out_size, void* d_ws, size_t ws_size,
                              hipStream_t stream) {
    const float* emb      = (const float*)d_in[0];
    const float* ref_curv = (const float*)d_in[1];
    const float* ref_dist = (const float*)d_in[2];
    float* out = (float*)d_out;

    float*  sq       = (float*)d_ws;                       // N
    float*  row_sum  = sq + N;                             // N
    float*  curv_err = row_sum + N;                        // N
    float*  pd2      = curv_err + N;                       // N*128
    int*    pidx     = (int*)(pd2 + (size_t)N * NPART);    // N*128
    int*    knn      = pidx + (size_t)N * NPART;           // N*K
    __bf16* embh     = (__bf16*)(knn + (size_t)N * K);     // N*D bf16 (8 MB)

    k_cast_sqnorm<<<N / 4, 256, 0, stream>>>(emb, sq, embh);
    k_knn<<<512, 256, 0, stream>>>(embh, sq, pd2, pidx);
    k_merge<<<N / 256, 256, 0, stream>>>(pd2, pidx, knn, row_sum);
    k_curv<<<N / 4, 256, 0, stream>>>(emb, knn, row_sum, ref_curv, curv_err);
    k_final<<<1, 1024, 0, stream>>>(curv_err, row_sum, ref_dist, out);
}